// Round 10
// baseline (275.139 us; speedup 1.0000x reference)
//
#include <hip/hip_runtime.h>
#include <hip/hip_bf16.h>

// B=4, N=2048, D_MODEL=512, H=4, DK=64, DV=128. fp32 in/out, bf16 MFMA.
// Softmax over BATCH axis (4 values) -> in-register per lane.
// R18: attn occupancy 2 -> 3 blocks/CU. Diagnosis: ~50% latency stalls at
// MfmaUtil 16 / VALU 29 / Occ 20 -- capped by LDS 64KB AND VGPR 120.
// (a) pl single-buffered 32KB (2 barriers/iter: write->read and
// read->next-write guards); (b) aq loads moved inside the iteration
// (rematerialized from L2-hot Qp, frees 32 pinned VGPRs), vf per-kq (16
// live); (c) __launch_bounds__(512,6) forces VGPR<=85 -> 6 waves/SIMD.
// Everything else byte-identical to R17 (2 partials, swizzled GEMMs,
// prep tile-transpose, XCD-grouped M-panels).

typedef __attribute__((ext_vector_type(8))) short short8;   // 8 x bf16
typedef __attribute__((ext_vector_type(4))) float floatx4;  // MFMA 16x16 acc
typedef unsigned short u16;
typedef unsigned int u32;

#define MFMA16(a, b, c) __builtin_amdgcn_mfma_f32_16x16x32_bf16((a), (b), (c), 0, 0, 0)

__device__ __forceinline__ u16 f2bf(float f) {
    union { float f; unsigned u; } v; v.f = f;
    unsigned r = v.u + 0x7fffu + ((v.u >> 16) & 1u);  // RNE
    return (u16)(r >> 16);
}

__device__ __forceinline__ float bf2f(u16 b) {
    union { unsigned u; float f; } v; v.u = ((u32)b) << 16;
    return v.f;
}

__device__ __forceinline__ u32 pk2bf(float a, float b) {
#if __has_builtin(__builtin_amdgcn_cvt_pk_bf16_f32)
    typedef __attribute__((ext_vector_type(2))) __bf16 bf16x2;
    union { bf16x2 v; u32 u; } c;
    c.v = __builtin_amdgcn_cvt_pk_bf16_f32(a, b);
    return c.u;
#else
    return (u32)f2bf(a) | ((u32)f2bf(b) << 16);
#endif
}

__device__ __forceinline__ float ex2(float x) {
#if __has_builtin(__builtin_amdgcn_exp2f)
    return __builtin_amdgcn_exp2f(x);
#else
    return exp2f(x);
#endif
}

// async global->LDS, 16B per lane. LDS dest wave-uniform base + lane*16B.
__device__ __forceinline__ void gload_lds16(const u16* g, u16* l) {
    __builtin_amdgcn_global_load_lds(
        (const __attribute__((address_space(1))) void*)(const void*)g,
        (__attribute__((address_space(3))) void*)(void*)l, 16, 0, 0);
}

// ------- merged prep: cast X (blocks [0,4096)) + weight transpose --------
// Q columns pre-scaled by 0.125*log2(e) so S arrives in log2 domain.
__global__ __launch_bounds__(256) void prep_all_kernel(
    const float* __restrict__ x, u16* __restrict__ xb,
    const float* __restrict__ Wq, const float* __restrict__ Wk,
    const float* __restrict__ Wv, const float* __restrict__ Wo,
    u16* __restrict__ WallT, u16* __restrict__ WoT) {
    const int bid = blockIdx.x;
    const int tid = threadIdx.x;
    if (bid < 4096) {
        int i = bid * 256 + tid;  // 1,048,576 float4 groups exactly
        float4 v = ((const float4*)x)[i];
        ushort4 o;
        o.x = f2bf(v.x); o.y = f2bf(v.y); o.z = f2bf(v.z); o.w = f2bf(v.w);
        ((ushort4*)xb)[i] = o;
        return;
    }
    __shared__ u16 lds[64 * 80];         // [n-local][k-local], stride 80
    const int t = bid - 4096;            // [0,192)
    const int k0 = (t & 7) * 64;
    const int n0 = (t >> 3) * 64;        // [0,1536)
    const float* src; int ld, coff; float scale = 1.0f;
    u16* dst;
    if (n0 < 256)       { src = Wq; ld = 256; coff = n0;        dst = WallT + (size_t)n0 * 512; scale = 0.18033688011f; }
    else if (n0 < 512)  { src = Wk; ld = 256; coff = n0 - 256;  dst = WallT + (size_t)n0 * 512; }
    else if (n0 < 1024) { src = Wv; ld = 512; coff = n0 - 512;  dst = WallT + (size_t)n0 * 512; }
    else                { src = Wo; ld = 512; coff = n0 - 1024; dst = WoT + (size_t)(n0 - 1024) * 512; }
#pragma unroll
    for (int p = 0; p < 4; p++) {
        int r  = (tid >> 4) + p * 16;    // k-local [0,64)
        int c4 = (tid & 15) * 4;         // n-local, float4 group
        float4 v = *(const float4*)&src[(size_t)(k0 + r) * ld + coff + c4];
        lds[(c4 + 0) * 80 + r] = f2bf(v.x * scale);
        lds[(c4 + 1) * 80 + r] = f2bf(v.y * scale);
        lds[(c4 + 2) * 80 + r] = f2bf(v.z * scale);
        lds[(c4 + 3) * 80 + r] = f2bf(v.w * scale);
    }
    __syncthreads();
#pragma unroll
    for (int p = 0; p < 2; p++) {
        int nn = (tid >> 3) + p * 32;    // n-local
        int kk = (tid & 7) * 8;          // k-local, short8 group
        *(short8*)&dst[(size_t)nn * 512 + k0 + kk] = *(const short8*)&lds[nn * 80 + kk];
    }
}

// ------- QKV GEMM: C[M][N] = A[M][K]*BT[N][K]^T, 128x128 tile, 512 thr ----
// 8 waves as 2m x 4n, each wave 64x32 (4x2 c-frags). gl_lds staging,
// LDS stride 64, T2 swizzle: source col-group ^ (lane>>3); read slot
// (ki*4+quad) ^ (lq&7). XCD remap: bid%8 = XCD; XCD x owns 8 m-panels.
// Qp: ((((b*4+h)*128+qs)*2+ki)*64+lane)*8+j
// Kp: ((((((b*4+h)*32+kt)*2+half)*2+nj)*2+ki)*64+lane)*8+j
// Vp: ((((((b*4+h)*32+kt)*2+half)*4+ni)*2+w)*64+lane)*8+j
__global__ __launch_bounds__(512) void gemm_qkv_kernel(
    const u16* __restrict__ A, const u16* __restrict__ BT,
    u16* __restrict__ Qp, u16* __restrict__ Kp, u16* __restrict__ Vp,
    int Kdim) {
    __shared__ u16 sm[16896];           // 33 KB; staging uses [0,16384)
    u16* Asl = sm;                       // 128x64, stride 64 (swizzled slots)
    u16* Bsl = sm + 8192;                // 128x64, stride 64 (swizzled slots)
    const int tid = threadIdx.x;
    const int bid0 = blockIdx.y * 8 + blockIdx.x;   // 512 WGs
    const int xcd = bid0 & 7, jj = bid0 >> 3;       // jj in [0,64)
    const int mbase = (xcd * 8 + (jj >> 3)) * 128;  // m-panel grouped per XCD
    const int nbase = (jj & 7) * 128;
    const int wave = tid >> 6, lane = tid & 63;
    const int wm = wave >> 2, wn = wave & 3;   // 2m x 4n
    const int lq = lane & 15, quad = lane >> 4;

    // staging: wave covers 16 rows of A and of B (2 issues of 8 rows each).
    const int scol = ((lane & 7) ^ (lane >> 3)) * 8;
    const u16* gA = A + (size_t)(mbase + wave * 16 + (lane >> 3)) * Kdim + scol;
    const u16* gB = BT + (size_t)(nbase + wave * 16 + (lane >> 3)) * Kdim + scol;
    u16* lA = &Asl[(wave * 16) * 64];
    u16* lB = &Bsl[(wave * 16) * 64];

    const floatx4 z4 = {0.f, 0.f, 0.f, 0.f};
    floatx4 acc[4][2];
#pragma unroll
    for (int i = 0; i < 4; i++)
#pragma unroll
        for (int j = 0; j < 2; j++) acc[i][j] = z4;

    const int nk = Kdim >> 6;
    for (int kk = 0; kk < nk; kk++) {
        const int kb = kk << 6;
        if (kk) __syncthreads();
#pragma unroll
        for (int i = 0; i < 2; i++) {
            gload_lds16(gA + kb + (size_t)(i * 8) * Kdim, lA + (i * 8) * 64);
            gload_lds16(gB + kb + (size_t)(i * 8) * Kdim, lB + (i * 8) * 64);
        }
        __syncthreads();
#pragma unroll
        for (int ki = 0; ki < 2; ki++) {
            short8 af[4], bf[2];
#pragma unroll
            for (int mi = 0; mi < 4; mi++)
                af[mi] = *(const short8*)&Asl[(wm * 64 + mi * 16 + lq) * 64 +
                                              (((ki * 4 + quad) ^ (lq & 7)) * 8)];
#pragma unroll
            for (int ni = 0; ni < 2; ni++)
                bf[ni] = *(const short8*)&Bsl[(wn * 32 + ni * 16 + lq) * 64 +
                                              (((ki * 4 + quad) ^ (lq & 7)) * 8)];
#pragma unroll
            for (int mi = 0; mi < 4; mi++)
#pragma unroll
                for (int ni = 0; ni < 2; ni++)
                    acc[mi][ni] = MFMA16(af[mi], bf[ni], acc[mi][ni]);
        }
    }
    // ---- epilogue phase 1: C-tile -> sm (stride 132; V-tiles transposed).
    __syncthreads();
    const bool vtile = (nbase >= 512);
#pragma unroll
    for (int mi = 0; mi < 4; mi++)
#pragma unroll
        for (int ni = 0; ni < 2; ni++) {
            int cl = wn * 32 + ni * 16 + lq;
#pragma unroll
            for (int r = 0; r < 4; r++) {
                int rl = wm * 64 + mi * 16 + quad * 4 + r;
                if (vtile) sm[cl * 132 + rl] = f2bf(acc[mi][ni][r]);  // transposed
                else       sm[rl * 132 + cl] = f2bf(acc[mi][ni][r]);
            }
        }
    __syncthreads();
    // ---- phase 2: 32 coalesced 1KB wave-lines (4 per wave). ----
    const int b = mbase >> 11;
    const int keyb = mbase & 2047;
    if (nbase < 256) {                        // Q tile
        const int hq = nbase >> 6;           // {0,2}
        const int qs_base = keyb >> 4;
#pragma unroll
        for (int t = 0; t < 4; t++) {
            int l = wave * 4 + t;
            int qs2 = l >> 2, h2 = (l >> 1) & 1, ki = l & 1;
            int qd = lane >> 4, lqq = lane & 15;
            short8 v = *(const short8*)&sm[(qs2 * 16 + lqq) * 132 + h2 * 64 + ki * 32 + qd * 8];
            int h = hq + h2;
            size_t base = ((size_t)(((b * 4 + h) * 128 + (qs_base + qs2)) * 2 + ki) * 64 + lane) << 3;
            *(short8*)&Qp[base] = v;
        }
    } else if (nbase < 512) {                 // K tile
        const int hb = (nbase - 256) >> 6;   // {0,2}
        const int ktb = keyb >> 6;
#pragma unroll
        for (int t = 0; t < 4; t++) {
            int l = wave * 4 + t;
            int kt2 = l >> 4, hf = (l >> 3) & 1, nj = (l >> 2) & 1;
            int h2 = (l >> 1) & 1, ki = l & 1;
            int quadk = lane >> 4, lqk = lane & 15;
            short8 v = *(const short8*)&sm[(kt2 * 64 + hf * 32 + lqk * 2 + nj) * 132 +
                                           h2 * 64 + ki * 32 + quadk * 8];
            int h = hb + h2;
            size_t base = ((size_t)(((((b * 4 + h) * 32 + (ktb + kt2)) * 2 + hf) * 2 + nj)
                                    * 2 + ki) * 64 + lane) << 3;
            *(short8*)&Kp[base] = v;
        }
    } else {                                  // V tile (sm transposed)
        const int h = (nbase - 512) >> 7;    // tile spans one head
        const int ktb = keyb >> 6;
#pragma unroll
        for (int t = 0; t < 4; t++) {
            int l = wave * 4 + t;
            int kt2 = l >> 4, hf = (l >> 3) & 1, niv = (l >> 1) & 3, wv = l & 1;
            int quadv = lane >> 4, lqv = lane & 15;
            short8 v = *(const short8*)&sm[(hf * 64 + niv * 16 + lqv) * 132 +
                                           kt2 * 64 + wv * 32 + quadv * 8];
            size_t base = ((size_t)(((((b * 4 + h) * 32 + (ktb + kt2)) * 2 + hf) * 4 + niv)
                                    * 2 + wv) * 64 + lane) << 3;
            *(short8*)&Vp[base] = v;
        }
    }
}

// ------- out GEMM: C[M][N] fp32 = (A0+A1)[M][K] * BT[N][K]^T --------------
// 64x128 tile, 512 thr, 8 waves as 2m x 4n, each wave 32x32 (2x2 c-frags).
// A-staging reg-sums the 2 ck-partials; ds_write addr swizzled (both-sides).
// B staged via gload_lds with pre-swizzled source. Reads XOR slot with
// (lq&7). 2 WG/CU x 8 waves = 16 waves/CU. LDS: A 8KB + B 16KB.
__global__ __launch_bounds__(512) void gemm_out_kernel(
    const u16* __restrict__ A, const u16* __restrict__ BT,
    float* __restrict__ Cf, int Kdim, int ldc) {
    __shared__ u16 Asl[64 * 64];
    __shared__ u16 Bsl[128 * 64];
    const int tid = threadIdx.x;
    const int bid0 = blockIdx.y * 4 + blockIdx.x;   // 512 WGs
    const int xcd = bid0 & 7, jj = bid0 >> 3;       // jj in [0,64)
    const int mbase = (xcd * 16 + (jj >> 2)) * 64;  // m-panel grouped per XCD
    const int nbase = (jj & 3) * 128;
    const int wave = tid >> 6, lane = tid & 63;
    const int wm = wave >> 2, wn = wave & 3;
    const int lq = lane & 15, quad = lane >> 4;
    const size_t S = (size_t)8192 * 512;  // partial stride (elements)

    const u16* gA = A + (size_t)(mbase + wave * 8 + (lane >> 3)) * Kdim + (lane & 7) * 8;
    const u16* gB = BT + (size_t)(nbase + wave * 16 + (lane >> 3)) * Kdim +
                    (((lane & 7) ^ (lane >> 3)) * 8);
    u16* lAw = &Asl[(wave * 8 + (lane >> 3)) * 64 + (((lane & 7) ^ (lane >> 3)) * 8)];
    u16* lB = &Bsl[(wave * 16) * 64];

    const floatx4 z4 = {0.f, 0.f, 0.f, 0.f};
    floatx4 acc[2][2];
#pragma unroll
    for (int i = 0; i < 2; i++)
#pragma unroll
        for (int j = 0; j < 2; j++) acc[i][j] = z4;

    const int nk = Kdim >> 6;
    for (int kk = 0; kk < nk; kk++) {
        const int kb = kk << 6;
        // issue partial loads early: latency hides under prior MFMAs
        short8 p0 = *(const short8*)(gA + kb);
        short8 p1 = *(const short8*)(gA + kb + S);
        if (kk) __syncthreads();
        gload_lds16(gB + kb, lB);
        gload_lds16(gB + kb + (size_t)8 * Kdim, lB + 8 * 64);
        short8 o;
#pragma unroll
        for (int j2 = 0; j2 < 8; j2++) {
            float s = bf2f((u16)p0[j2]) + bf2f((u16)p1[j2]);
            o[j2] = (short)f2bf(s);
        }
        *(short8*)lAw = o;
        __syncthreads();
#pragma unroll
        for (int ki = 0; ki < 2; ki++) {
            short8 af[2], bf[2];
#pragma unroll
            for (int mi = 0; mi < 2; mi++)
                af[mi] = *(const short8*)&Asl[(wm * 32 + mi * 16 + lq) * 64 +
                                              (((ki * 4 + quad) ^ (lq & 7)) * 8)];
#pragma unroll
            for (int ni = 0; ni < 2; ni++)
                bf[ni] = *(const short8*)&Bsl[(wn * 32 + ni * 16 + lq) * 64 +
                                              (((ki * 4 + quad) ^ (lq & 7)) * 8)];
#pragma unroll
            for (int mi = 0; mi < 2; mi++)
#pragma unroll
                for (int ni = 0; ni < 2; ni++)
                    acc[mi][ni] = MFMA16(af[mi], bf[ni], acc[mi][ni]);
        }
    }
#pragma unroll
    for (int mi = 0; mi < 2; mi++)
#pragma unroll
        for (int ni = 0; ni < 2; ni++)
#pragma unroll
            for (int r = 0; r < 4; r++)
                Cf[(size_t)(mbase + wm * 32 + mi * 16 + quad * 4 + r) * ldc +
                   (nbase + wn * 32 + ni * 16 + lq)] = acc[mi][ni][r];
}

// ---------------- fused attention (R18: 3 blocks/CU) ----------------------
// Geometry = R17 (qt64 x ck2; slice=(h,ck)=bx&7 XCD-local). Occupancy
// levers: pl single-buffered 32KB (2 barriers/iter), aq reloaded per
// iteration (L2-hot), vf per-kq, __launch_bounds__(512,6) -> VGPR<=85.
__global__ __launch_bounds__(512, 6) void attn_kernel(const u16* __restrict__ Qp,
                                                      const u16* __restrict__ Kp,
                                                      const u16* __restrict__ Vp,
                                                      u16* __restrict__ Pp) {
    __shared__ u16 pl[4 * 4096];  // [ktq*2+mi][4b*16q][64 keys] = 32 KB
    const int bx = blockIdx.x;
    const int h = bx & 3;
    const int ck = (bx >> 2) & 1;
    const int qt = bx >> 3;                     // [0,64)
    const int tid = threadIdx.x;
    const int wave = tid >> 6, lane = tid & 63;
    const int mi = wave & 1;                    // S: qs unit
    const int half = (wave >> 1) & 1;           // S: key half
    const int ktq = wave >> 2;                  // S: which of the 2 kt
    const int dq = wave;                        // PV: dv-16-slice
    const int half_v = dq >> 2, ni_v = dq & 3;
    const int lq = lane & 15, quad = lane >> 4;
    const int qs = qt * 2 + mi;                 // [0,128)

    const floatx4 z4 = {0.f, 0.f, 0.f, 0.f};
    floatx4 oacc[4][2];  // [b][m2]
#pragma unroll
    for (int b = 0; b < 4; b++)
#pragma unroll
        for (int m2 = 0; m2 < 2; m2++) oacc[b][m2] = z4;

    const int ckb = ck * 16;
    u16* plb = &pl[(ktq * 2 + mi) * 4096];
    for (int it = 0; it < 8; it++) {
        const int kt = ckb + it * 2 + ktq;      // this wave's S-phase kt
        floatx4 s[4][2];
#pragma unroll
        for (int b = 0; b < 4; b++) {
            // Q frags reloaded per iteration (rematerializable; frees VGPRs)
            const u16* qb = Qp + ((size_t)((((b * 4 + h) * 128 + qs) * 2) * 64 + lane) << 3);
            short8 aq0 = *(const short8*)qb;
            short8 aq1 = *(const short8*)(qb + 512);
            const u16* kb = Kp +
                ((size_t)((((b * 4 + h) * 32 + kt) * 2 + half) * 2) << 10) +
                lane * 8;
#pragma unroll
            for (int nj = 0; nj < 2; nj++) {
                s[b][nj] = z4;
                s[b][nj] = MFMA16(aq0, *(const short8*)(kb + (nj * 2 + 0) * 512), s[b][nj]);
                s[b][nj] = MFMA16(aq1, *(const short8*)(kb + (nj * 2 + 1) * 512), s[b][nj]);
            }
        }
#pragma unroll
        for (int r = 0; r < 4; r++) {
            float e0a = ex2(s[0][0][r]), e0b = ex2(s[0][1][r]);
            float e1a = ex2(s[1][0][r]), e1b = ex2(s[1][1][r]);
            float e2a = ex2(s[2][0][r]), e2b = ex2(s[2][1][r]);
            float e3a = ex2(s[3][0][r]), e3b = ex2(s[3][1][r]);
            float ia = __builtin_amdgcn_rcpf(e0a + e1a + e2a + e3a);
            float ib = __builtin_amdgcn_rcpf(e0b + e1b + e2b + e3b);
            int q = quad * 4 + r;
            int col = (half * 32 + 2 * lq) ^ ((q & 7) * 8);  // XOR swizzle
            *(u32*)&plb[(0 * 16 + q) * 64 + col] = pk2bf(e0a * ia, e0b * ib);
            *(u32*)&plb[(1 * 16 + q) * 64 + col] = pk2bf(e1a * ia, e1b * ib);
            *(u32*)&plb[(2 * 16 + q) * 64 + col] = pk2bf(e2a * ia, e2b * ib);
            *(u32*)&plb[(3 * 16 + q) * 64 + col] = pk2bf(e3a * ia, e3b * ib);
        }
        __syncthreads();                         // S-writes -> PV-reads
        const int sw = (lq & 7) * 8;
#pragma unroll
        for (int kq = 0; kq < 2; kq++) {
            const int ktv = ckb + it * 2 + kq;
            short8 vf[4][2];                     // per-kq JIT: 16 live VGPRs
#pragma unroll
            for (int b = 0; b < 4; b++) {
                const u16* vb = Vp +
                    ((size_t)(((((b * 4 + h) * 32 + ktv) * 2 + half_v) * 4 + ni_v) * 2) << 9) +
                    lane * 8;
                vf[b][0] = *(const short8*)vb;
                vf[b][1] = *(const short8*)(vb + 512);
            }
#pragma unroll
            for (int b = 0; b < 4; b++) {
#pragma unroll
                for (int m2 = 0; m2 < 2; m2++) {
                    const u16* pm = pl + (kq * 2 + m2) * 4096;
                    short8 ap0 = *(const short8*)&pm[(b * 16 + lq) * 64 + ((quad * 8) ^ sw)];
                    short8 ap1 = *(const short8*)&pm[(b * 16 + lq) * 64 + ((32 + quad * 8) ^ sw)];
                    oacc[b][m2] = MFMA16(ap0, vf[b][0], oacc[b][m2]);
                    oacc[b][m2] = MFMA16(ap1, vf[b][1], oacc[b][m2]);
                }
            }
        }
        __syncthreads();                         // PV-reads -> next S-writes
    }
    u16* Pc = Pp + (size_t)ck * (8192 * 512);
#pragma unroll
    for (int b = 0; b < 4; b++)
#pragma unroll
        for (int m2 = 0; m2 < 2; m2++)
#pragma unroll
            for (int r = 0; r < 4; r++)
                Pc[(size_t)(b * 2048 + qt * 32 + m2 * 16 + quad * 4 + r) * 512 +
                   h * 128 + dq * 16 + lq] = f2bf(oacc[b][m2][r]);
}

extern "C" void kernel_launch(void* const* d_in, const int* in_sizes, int n_in,
                              void* d_out, int out_size, void* d_ws, size_t ws_size,
                              hipStream_t stream) {
    const float* x  = (const float*)d_in[0];
    const float* Wq = (const float*)d_in[1];
    const float* Wk = (const float*)d_in[2];
    const float* Wv = (const float*)d_in[3];
    const float* Wo = (const float*)d_in[4];
    float* out = (float*)d_out;

    // Workspace map. Pp[0..2) partials occupy [0, 16MB); Xb (8MB) and
    // WallT (1MB) are OVERLAID at the start -- both dead before attn
    // writes partials. gemm_out reads both partials directly.
    char* ws = (char*)d_ws;
    u16* Pp    = (u16*)ws;                                   // 2 x 8MB bf16
    u16* Xb    = (u16*)ws;                                   // overlay [0,8MB)
    u16* WallT = (u16*)(ws + (size_t)8 * 1024 * 1024);       // overlay [8,9MB)
    char* tail = ws + (size_t)32 * 1024 * 1024;
    u16* WoT   = (u16*)tail; tail += (size_t)512 * 512 * 2;  // 0.5MB
    u16* Qp    = (u16*)tail; tail += (size_t)8192 * 256 * 2; // 4MB
    u16* Kp    = (u16*)tail; tail += (size_t)8192 * 256 * 2; // 4MB
    u16* Vp    = (u16*)tail; tail += (size_t)8192 * 512 * 2; // 8MB

    prep_all_kernel<<<4288, 256, 0, stream>>>(x, Xb, Wq, Wk, Wv, Wo, WallT, WoT);
    // QKV = X @ [Wq|Wk|Wv] : [8192,1024] -> Qp/Kp/Vp packed (512 WGs, 512thr)
    gemm_qkv_kernel<<<dim3(8, 64), 512, 0, stream>>>(Xb, WallT, Qp, Kp, Vp, 512);
    attn_kernel<<<512, 512, 0, stream>>>(Qp, Kp, Vp, Pp);
    // out = (P0+P1) @ Wo : fp32 (512 WGs, 512thr, 64x128 tiles)
    gemm_out_kernel<<<dim3(4, 128), 512, 0, stream>>>(Pp, WoT, out, 512, 512);
}

// Round 11
// 157.345 us; speedup vs baseline: 1.7486x; 1.7486x over previous
//
#include <hip/hip_runtime.h>
#include <hip/hip_bf16.h>

// B=4, N=2048, D_MODEL=512, H=4, DK=64, DV=128. fp32 in/out, bf16 MFMA.
// Softmax over BATCH axis (4 values) -> in-register per lane.
// R19: (1) attn reverted to R17-exact (R18's launch_bounds(512,6) forced
// VGPR 40 << ~112 live state -> 700MB scratch spill traffic, 181-236us.
// Occupancy is structurally walled at 2 blocks/CU for this attn). 
// (2) gemm_qkv BK 64 -> 128: 4 K-steps (was 8), 32 MFMAs/wave/step
// (was 16), barrier drains halved. LDS 64KB, occupancy stays 2 blocks/CU
// (m132's BK=128 regression was a 3->2 occupancy drop -- absent here).
// T2 swizzle generalized to 16 slots/row: source colgroup ^ (row&15),
// read slot (ki*4+quad) ^ lq. Bit-identical math.
// Kept: 2 partials; R16 swizzles in gemm_out; prep tile-transpose;
// XCD-grouped M-panels; reduce fused into gemm_out.

typedef __attribute__((ext_vector_type(8))) short short8;   // 8 x bf16
typedef __attribute__((ext_vector_type(4))) float floatx4;  // MFMA 16x16 acc
typedef unsigned short u16;
typedef unsigned int u32;

#define MFMA16(a, b, c) __builtin_amdgcn_mfma_f32_16x16x32_bf16((a), (b), (c), 0, 0, 0)

__device__ __forceinline__ u16 f2bf(float f) {
    union { float f; unsigned u; } v; v.f = f;
    unsigned r = v.u + 0x7fffu + ((v.u >> 16) & 1u);  // RNE
    return (u16)(r >> 16);
}

__device__ __forceinline__ float bf2f(u16 b) {
    union { unsigned u; float f; } v; v.u = ((u32)b) << 16;
    return v.f;
}

__device__ __forceinline__ u32 pk2bf(float a, float b) {
#if __has_builtin(__builtin_amdgcn_cvt_pk_bf16_f32)
    typedef __attribute__((ext_vector_type(2))) __bf16 bf16x2;
    union { bf16x2 v; u32 u; } c;
    c.v = __builtin_amdgcn_cvt_pk_bf16_f32(a, b);
    return c.u;
#else
    return (u32)f2bf(a) | ((u32)f2bf(b) << 16);
#endif
}

__device__ __forceinline__ float ex2(float x) {
#if __has_builtin(__builtin_amdgcn_exp2f)
    return __builtin_amdgcn_exp2f(x);
#else
    return exp2f(x);
#endif
}

// async global->LDS, 16B per lane. LDS dest wave-uniform base + lane*16B.
__device__ __forceinline__ void gload_lds16(const u16* g, u16* l) {
    __builtin_amdgcn_global_load_lds(
        (const __attribute__((address_space(1))) void*)(const void*)g,
        (__attribute__((address_space(3))) void*)(void*)l, 16, 0, 0);
}

// ------- merged prep: cast X (blocks [0,4096)) + weight transpose --------
// Q columns pre-scaled by 0.125*log2(e) so S arrives in log2 domain.
__global__ __launch_bounds__(256) void prep_all_kernel(
    const float* __restrict__ x, u16* __restrict__ xb,
    const float* __restrict__ Wq, const float* __restrict__ Wk,
    const float* __restrict__ Wv, const float* __restrict__ Wo,
    u16* __restrict__ WallT, u16* __restrict__ WoT) {
    const int bid = blockIdx.x;
    const int tid = threadIdx.x;
    if (bid < 4096) {
        int i = bid * 256 + tid;  // 1,048,576 float4 groups exactly
        float4 v = ((const float4*)x)[i];
        ushort4 o;
        o.x = f2bf(v.x); o.y = f2bf(v.y); o.z = f2bf(v.z); o.w = f2bf(v.w);
        ((ushort4*)xb)[i] = o;
        return;
    }
    __shared__ u16 lds[64 * 80];         // [n-local][k-local], stride 80
    const int t = bid - 4096;            // [0,192)
    const int k0 = (t & 7) * 64;
    const int n0 = (t >> 3) * 64;        // [0,1536)
    const float* src; int ld, coff; float scale = 1.0f;
    u16* dst;
    if (n0 < 256)       { src = Wq; ld = 256; coff = n0;        dst = WallT + (size_t)n0 * 512; scale = 0.18033688011f; }
    else if (n0 < 512)  { src = Wk; ld = 256; coff = n0 - 256;  dst = WallT + (size_t)n0 * 512; }
    else if (n0 < 1024) { src = Wv; ld = 512; coff = n0 - 512;  dst = WallT + (size_t)n0 * 512; }
    else                { src = Wo; ld = 512; coff = n0 - 1024; dst = WoT + (size_t)(n0 - 1024) * 512; }
#pragma unroll
    for (int p = 0; p < 4; p++) {
        int r  = (tid >> 4) + p * 16;    // k-local [0,64)
        int c4 = (tid & 15) * 4;         // n-local, float4 group
        float4 v = *(const float4*)&src[(size_t)(k0 + r) * ld + coff + c4];
        lds[(c4 + 0) * 80 + r] = f2bf(v.x * scale);
        lds[(c4 + 1) * 80 + r] = f2bf(v.y * scale);
        lds[(c4 + 2) * 80 + r] = f2bf(v.z * scale);
        lds[(c4 + 3) * 80 + r] = f2bf(v.w * scale);
    }
    __syncthreads();
#pragma unroll
    for (int p = 0; p < 2; p++) {
        int nn = (tid >> 3) + p * 32;    // n-local
        int kk = (tid & 7) * 8;          // k-local, short8 group
        *(short8*)&dst[(size_t)nn * 512 + k0 + kk] = *(const short8*)&lds[nn * 80 + kk];
    }
}

// ------- QKV GEMM: C[M][N] = A[M][K]*BT[N][K]^T, 128x128 tile, BK=128 ----
// 512 thr, 8 waves as 2m x 4n, each wave 64x32 (4x2 c-frags). 4 K-steps,
// 32 MFMAs/wave/step. LDS 64KB: A[128][128] + B[128][128] u16, row-major.
// T2 swizzle (16 slots/row): source colgroup = (lane&15) ^ (row&15);
// read slot = (ki*4+quad) ^ lq. Staging: 4 gloads each for A and B per
// wave per step (each gload = 4 rows x 256B). Epilogue reuses sm[0,33KB).
// XCD remap: bid%8 = XCD; XCD x owns 8 m-panels.
// Qp: ((((b*4+h)*128+qs)*2+ki)*64+lane)*8+j
// Kp: ((((((b*4+h)*32+kt)*2+half)*2+nj)*2+ki)*64+lane)*8+j
// Vp: ((((((b*4+h)*32+kt)*2+half)*4+ni)*2+w)*64+lane)*8+j
__global__ __launch_bounds__(512) void gemm_qkv_kernel(
    const u16* __restrict__ A, const u16* __restrict__ BT,
    u16* __restrict__ Qp, u16* __restrict__ Kp, u16* __restrict__ Vp,
    int Kdim) {
    __shared__ u16 sm[32768];            // 64 KB
    u16* Asl = sm;                       // [128][128], stride 128
    u16* Bsl = sm + 16384;               // [128][128], stride 128
    const int tid = threadIdx.x;
    const int bid0 = blockIdx.y * 8 + blockIdx.x;   // 512 WGs
    const int xcd = bid0 & 7, jj = bid0 >> 3;       // jj in [0,64)
    const int mbase = (xcd * 8 + (jj >> 3)) * 128;  // m-panel grouped per XCD
    const int nbase = (jj & 7) * 128;
    const int wave = tid >> 6, lane = tid & 63;
    const int wm = wave >> 2, wn = wave & 3;   // 2m x 4n
    const int lq = lane & 15, quad = lane >> 4;
    const int rsub = lane >> 4;                // staging row-within-gload [0,4)
    const int csub = lane & 15;                // staging 16B col-slot [0,16)

    const floatx4 z4 = {0.f, 0.f, 0.f, 0.f};
    floatx4 acc[4][2];
#pragma unroll
    for (int i = 0; i < 4; i++)
#pragma unroll
        for (int j = 0; j < 2; j++) acc[i][j] = z4;

    const int nk = Kdim >> 7;                  // 4 steps of BK=128
    for (int kk = 0; kk < nk; kk++) {
        const int kb = kk << 7;
        if (kk) __syncthreads();
#pragma unroll
        for (int i = 0; i < 4; i++) {
            int rloc = wave * 16 + i * 4 + rsub;           // local row [0,128)
            int cg = csub ^ ((i * 4 + rsub) & 15);         // swizzled colgroup
            gload_lds16(A + (size_t)(mbase + rloc) * Kdim + kb + cg * 8,
                        Asl + (wave * 16 + i * 4) * 128);
            gload_lds16(BT + (size_t)(nbase + rloc) * Kdim + kb + cg * 8,
                        Bsl + (wave * 16 + i * 4) * 128);
        }
        __syncthreads();
#pragma unroll
        for (int ki = 0; ki < 4; ki++) {
            short8 af[4], bf[2];
#pragma unroll
            for (int mi = 0; mi < 4; mi++)
                af[mi] = *(const short8*)&Asl[(wm * 64 + mi * 16 + lq) * 128 +
                                              (((ki * 4 + quad) ^ lq) * 8)];
#pragma unroll
            for (int ni = 0; ni < 2; ni++)
                bf[ni] = *(const short8*)&Bsl[(wn * 32 + ni * 16 + lq) * 128 +
                                              (((ki * 4 + quad) ^ lq) * 8)];
#pragma unroll
            for (int mi = 0; mi < 4; mi++)
#pragma unroll
                for (int ni = 0; ni < 2; ni++)
                    acc[mi][ni] = MFMA16(af[mi], bf[ni], acc[mi][ni]);
        }
    }
    // ---- epilogue phase 1: C-tile -> sm (stride 132; V-tiles transposed).
    __syncthreads();
    const bool vtile = (nbase >= 512);
#pragma unroll
    for (int mi = 0; mi < 4; mi++)
#pragma unroll
        for (int ni = 0; ni < 2; ni++) {
            int cl = wn * 32 + ni * 16 + lq;
#pragma unroll
            for (int r = 0; r < 4; r++) {
                int rl = wm * 64 + mi * 16 + quad * 4 + r;
                if (vtile) sm[cl * 132 + rl] = f2bf(acc[mi][ni][r]);  // transposed
                else       sm[rl * 132 + cl] = f2bf(acc[mi][ni][r]);
            }
        }
    __syncthreads();
    // ---- phase 2: 32 coalesced 1KB wave-lines (4 per wave). ----
    const int b = mbase >> 11;
    const int keyb = mbase & 2047;
    if (nbase < 256) {                        // Q tile
        const int hq = nbase >> 6;           // {0,2}
        const int qs_base = keyb >> 4;
#pragma unroll
        for (int t = 0; t < 4; t++) {
            int l = wave * 4 + t;
            int qs2 = l >> 2, h2 = (l >> 1) & 1, ki = l & 1;
            int qd = lane >> 4, lqq = lane & 15;
            short8 v = *(const short8*)&sm[(qs2 * 16 + lqq) * 132 + h2 * 64 + ki * 32 + qd * 8];
            int h = hq + h2;
            size_t base = ((size_t)(((b * 4 + h) * 128 + (qs_base + qs2)) * 2 + ki) * 64 + lane) << 3;
            *(short8*)&Qp[base] = v;
        }
    } else if (nbase < 512) {                 // K tile
        const int hb = (nbase - 256) >> 6;   // {0,2}
        const int ktb = keyb >> 6;
#pragma unroll
        for (int t = 0; t < 4; t++) {
            int l = wave * 4 + t;
            int kt2 = l >> 4, hf = (l >> 3) & 1, nj = (l >> 2) & 1;
            int h2 = (l >> 1) & 1, ki = l & 1;
            int quadk = lane >> 4, lqk = lane & 15;
            short8 v = *(const short8*)&sm[(kt2 * 64 + hf * 32 + lqk * 2 + nj) * 132 +
                                           h2 * 64 + ki * 32 + quadk * 8];
            int h = hb + h2;
            size_t base = ((size_t)(((((b * 4 + h) * 32 + (ktb + kt2)) * 2 + hf) * 2 + nj)
                                    * 2 + ki) * 64 + lane) << 3;
            *(short8*)&Kp[base] = v;
        }
    } else {                                  // V tile (sm transposed)
        const int h = (nbase - 512) >> 7;    // tile spans one head
        const int ktb = keyb >> 6;
#pragma unroll
        for (int t = 0; t < 4; t++) {
            int l = wave * 4 + t;
            int kt2 = l >> 4, hf = (l >> 3) & 1, niv = (l >> 1) & 3, wv = l & 1;
            int quadv = lane >> 4, lqv = lane & 15;
            short8 v = *(const short8*)&sm[(hf * 64 + niv * 16 + lqv) * 132 +
                                           kt2 * 64 + wv * 32 + quadv * 8];
            size_t base = ((size_t)(((((b * 4 + h) * 32 + (ktb + kt2)) * 2 + hf) * 4 + niv)
                                    * 2 + wv) * 64 + lane) << 3;
            *(short8*)&Vp[base] = v;
        }
    }
}

// ------- out GEMM: C[M][N] fp32 = (A0+A1)[M][K] * BT[N][K]^T --------------
// 64x128 tile, 512 thr, 8 waves as 2m x 4n, each wave 32x32 (2x2 c-frags).
// A-staging reg-sums the 2 ck-partials; ds_write addr swizzled (both-sides).
// B staged via gload_lds with pre-swizzled source. Reads XOR slot with
// (lq&7). 2 WG/CU x 8 waves = 16 waves/CU. LDS: A 8KB + B 16KB.
__global__ __launch_bounds__(512) void gemm_out_kernel(
    const u16* __restrict__ A, const u16* __restrict__ BT,
    float* __restrict__ Cf, int Kdim, int ldc) {
    __shared__ u16 Asl[64 * 64];
    __shared__ u16 Bsl[128 * 64];
    const int tid = threadIdx.x;
    const int bid0 = blockIdx.y * 4 + blockIdx.x;   // 512 WGs
    const int xcd = bid0 & 7, jj = bid0 >> 3;       // jj in [0,64)
    const int mbase = (xcd * 16 + (jj >> 2)) * 64;  // m-panel grouped per XCD
    const int nbase = (jj & 3) * 128;
    const int wave = tid >> 6, lane = tid & 63;
    const int wm = wave >> 2, wn = wave & 3;
    const int lq = lane & 15, quad = lane >> 4;
    const size_t S = (size_t)8192 * 512;  // partial stride (elements)

    const u16* gA = A + (size_t)(mbase + wave * 8 + (lane >> 3)) * Kdim + (lane & 7) * 8;
    const u16* gB = BT + (size_t)(nbase + wave * 16 + (lane >> 3)) * Kdim +
                    (((lane & 7) ^ (lane >> 3)) * 8);
    u16* lAw = &Asl[(wave * 8 + (lane >> 3)) * 64 + (((lane & 7) ^ (lane >> 3)) * 8)];
    u16* lB = &Bsl[(wave * 16) * 64];

    const floatx4 z4 = {0.f, 0.f, 0.f, 0.f};
    floatx4 acc[2][2];
#pragma unroll
    for (int i = 0; i < 2; i++)
#pragma unroll
        for (int j = 0; j < 2; j++) acc[i][j] = z4;

    const int nk = Kdim >> 6;
    for (int kk = 0; kk < nk; kk++) {
        const int kb = kk << 6;
        // issue partial loads early: latency hides under prior MFMAs
        short8 p0 = *(const short8*)(gA + kb);
        short8 p1 = *(const short8*)(gA + kb + S);
        if (kk) __syncthreads();
        gload_lds16(gB + kb, lB);
        gload_lds16(gB + kb + (size_t)8 * Kdim, lB + 8 * 64);
        short8 o;
#pragma unroll
        for (int j2 = 0; j2 < 8; j2++) {
            float s = bf2f((u16)p0[j2]) + bf2f((u16)p1[j2]);
            o[j2] = (short)f2bf(s);
        }
        *(short8*)lAw = o;
        __syncthreads();
#pragma unroll
        for (int ki = 0; ki < 2; ki++) {
            short8 af[2], bf[2];
#pragma unroll
            for (int mi = 0; mi < 2; mi++)
                af[mi] = *(const short8*)&Asl[(wm * 32 + mi * 16 + lq) * 64 +
                                              (((ki * 4 + quad) ^ (lq & 7)) * 8)];
#pragma unroll
            for (int ni = 0; ni < 2; ni++)
                bf[ni] = *(const short8*)&Bsl[(wn * 32 + ni * 16 + lq) * 64 +
                                              (((ki * 4 + quad) ^ (lq & 7)) * 8)];
#pragma unroll
            for (int mi = 0; mi < 2; mi++)
#pragma unroll
                for (int ni = 0; ni < 2; ni++)
                    acc[mi][ni] = MFMA16(af[mi], bf[ni], acc[mi][ni]);
        }
    }
#pragma unroll
    for (int mi = 0; mi < 2; mi++)
#pragma unroll
        for (int ni = 0; ni < 2; ni++)
#pragma unroll
            for (int r = 0; r < 4; r++)
                Cf[(size_t)(mbase + wm * 32 + mi * 16 + quad * 4 + r) * ldc +
                   (nbase + wn * 32 + ni * 16 + lq)] = acc[mi][ni][r];
}

// ---------------- fused attention (R17-exact: qt64 x ck2) ----------------
// 512 blocks: h=bx&3, ck=(bx>>2)&1, qt=bx>>3 in [0,64). slice=(h,ck)=bx&7
// XCD-local (XCD=bx%8), K+V 1.5MB/slice L2-resident. 32 q-rows, 16 kt
// (2/iter; S waves = mi2 x half2 x ktq2; PV loops ktq). pl dbuf 64KB.
__global__ __launch_bounds__(512) void attn_kernel(const u16* __restrict__ Qp,
                                                   const u16* __restrict__ Kp,
                                                   const u16* __restrict__ Vp,
                                                   u16* __restrict__ Pp) {
    __shared__ u16 pl[2 * 4 * 4096];  // 64 KB exactly
    const int bx = blockIdx.x;
    const int h = bx & 3;
    const int ck = (bx >> 2) & 1;
    const int qt = bx >> 3;                     // [0,64)
    const int tid = threadIdx.x;
    const int wave = tid >> 6, lane = tid & 63;
    const int mi = wave & 1;                    // S: qs unit
    const int half = (wave >> 1) & 1;           // S: key half
    const int ktq = wave >> 2;                  // S: which of the 2 kt
    const int dq = wave;                        // PV: dv-16-slice
    const int half_v = dq >> 2, ni_v = dq & 3;
    const int lq = lane & 15, quad = lane >> 4;
    const int qs = qt * 2 + mi;                 // [0,128)

    short8 aq[4][2];
#pragma unroll
    for (int b = 0; b < 4; b++)
#pragma unroll
        for (int ki = 0; ki < 2; ki++)
            aq[b][ki] = *(const short8*)&Qp[
                ((size_t)((((b * 4 + h) * 128 + qs) * 2 + ki) * 64 + lane) << 3)];

    const floatx4 z4 = {0.f, 0.f, 0.f, 0.f};
    floatx4 oacc[4][2];  // [b][m2]
#pragma unroll
    for (int b = 0; b < 4; b++)
#pragma unroll
        for (int m2 = 0; m2 < 2; m2++) oacc[b][m2] = z4;

    const int ckb = ck * 16;
    for (int it = 0; it < 8; it++) {
        const int kt = ckb + it * 2 + ktq;      // this wave's S-phase kt
        u16* plb = &pl[(((it & 1) * 2 + ktq) * 2 + mi) * 4096];
        floatx4 s[4][2];
#pragma unroll
        for (int b = 0; b < 4; b++) {
            const u16* kb = Kp +
                ((size_t)((((b * 4 + h) * 32 + kt) * 2 + half) * 2) << 10) +
                lane * 8;
#pragma unroll
            for (int nj = 0; nj < 2; nj++) {
                s[b][nj] = z4;
#pragma unroll
                for (int ki = 0; ki < 2; ki++)
                    s[b][nj] = MFMA16(aq[b][ki],
                                      *(const short8*)(kb + (nj * 2 + ki) * 512),
                                      s[b][nj]);
            }
        }
        // V frags for BOTH kt of this iteration (early issue; used after bar)
        short8 vf[2][4][2];
#pragma unroll
        for (int kq = 0; kq < 2; kq++) {
            const int ktv = ckb + it * 2 + kq;
#pragma unroll
            for (int b = 0; b < 4; b++) {
                const u16* vb = Vp +
                    ((size_t)(((((b * 4 + h) * 32 + ktv) * 2 + half_v) * 4 + ni_v) * 2) << 9) +
                    lane * 8;
                vf[kq][b][0] = *(const short8*)vb;
                vf[kq][b][1] = *(const short8*)(vb + 512);
            }
        }
#pragma unroll
        for (int r = 0; r < 4; r++) {
            float e0a = ex2(s[0][0][r]), e0b = ex2(s[0][1][r]);
            float e1a = ex2(s[1][0][r]), e1b = ex2(s[1][1][r]);
            float e2a = ex2(s[2][0][r]), e2b = ex2(s[2][1][r]);
            float e3a = ex2(s[3][0][r]), e3b = ex2(s[3][1][r]);
            float ia = __builtin_amdgcn_rcpf(e0a + e1a + e2a + e3a);
            float ib = __builtin_amdgcn_rcpf(e0b + e1b + e2b + e3b);
            int q = quad * 4 + r;
            int col = (half * 32 + 2 * lq) ^ ((q & 7) * 8);  // XOR swizzle
            *(u32*)&plb[(0 * 16 + q) * 64 + col] = pk2bf(e0a * ia, e0b * ib);
            *(u32*)&plb[(1 * 16 + q) * 64 + col] = pk2bf(e1a * ia, e1b * ib);
            *(u32*)&plb[(2 * 16 + q) * 64 + col] = pk2bf(e2a * ia, e2b * ib);
            *(u32*)&plb[(3 * 16 + q) * 64 + col] = pk2bf(e3a * ia, e3b * ib);
        }
        __syncthreads();
        const int sw = (lq & 7) * 8;
        u16* plbase = &pl[(it & 1) * 4 * 4096];
#pragma unroll
        for (int kq = 0; kq < 2; kq++) {
#pragma unroll
            for (int b = 0; b < 4; b++) {
#pragma unroll
                for (int m2 = 0; m2 < 2; m2++) {
                    const u16* pm = plbase + (kq * 2 + m2) * 4096;
                    short8 ap0 = *(const short8*)&pm[(b * 16 + lq) * 64 + ((quad * 8) ^ sw)];
                    short8 ap1 = *(const short8*)&pm[(b * 16 + lq) * 64 + ((32 + quad * 8) ^ sw)];
                    oacc[b][m2] = MFMA16(ap0, vf[kq][b][0], oacc[b][m2]);
                    oacc[b][m2] = MFMA16(ap1, vf[kq][b][1], oacc[b][m2]);
                }
            }
        }
    }
    u16* Pc = Pp + (size_t)ck * (8192 * 512);
#pragma unroll
    for (int b = 0; b < 4; b++)
#pragma unroll
        for (int m2 = 0; m2 < 2; m2++)
#pragma unroll
            for (int r = 0; r < 4; r++)
                Pc[(size_t)(b * 2048 + qt * 32 + m2 * 16 + quad * 4 + r) * 512 +
                   h * 128 + dq * 16 + lq] = f2bf(oacc[b][m2][r]);
}

extern "C" void kernel_launch(void* const* d_in, const int* in_sizes, int n_in,
                              void* d_out, int out_size, void* d_ws, size_t ws_size,
                              hipStream_t stream) {
    const float* x  = (const float*)d_in[0];
    const float* Wq = (const float*)d_in[1];
    const float* Wk = (const float*)d_in[2];
    const float* Wv = (const float*)d_in[3];
    const float* Wo = (const float*)d_in[4];
    float* out = (float*)d_out;

    // Workspace map. Pp[0..2) partials occupy [0, 16MB); Xb (8MB) and
    // WallT (1MB) are OVERLAID at the start -- both dead before attn
    // writes partials. gemm_out reads both partials directly.
    char* ws = (char*)d_ws;
    u16* Pp    = (u16*)ws;                                   // 2 x 8MB bf16
    u16* Xb    = (u16*)ws;                                   // overlay [0,8MB)
    u16* WallT = (u16*)(ws + (size_t)8 * 1024 * 1024);       // overlay [8,9MB)
    char* tail = ws + (size_t)32 * 1024 * 1024;
    u16* WoT   = (u16*)tail; tail += (size_t)512 * 512 * 2;  // 0.5MB
    u16* Qp    = (u16*)tail; tail += (size_t)8192 * 256 * 2; // 4MB
    u16* Kp    = (u16*)tail; tail += (size_t)8192 * 256 * 2; // 4MB
    u16* Vp    = (u16*)tail; tail += (size_t)8192 * 512 * 2; // 8MB

    prep_all_kernel<<<4288, 256, 0, stream>>>(x, Xb, Wq, Wk, Wv, Wo, WallT, WoT);
    // QKV = X @ [Wq|Wk|Wv] : [8192,1024] -> Qp/Kp/Vp packed (512 WGs, 512thr)
    gemm_qkv_kernel<<<dim3(8, 64), 512, 0, stream>>>(Xb, WallT, Qp, Kp, Vp, 512);
    attn_kernel<<<512, 512, 0, stream>>>(Qp, Kp, Vp, Pp);
    // out = (P0+P1) @ Wo : fp32 (512 WGs, 512thr, 64x128 tiles)
    gemm_out_kernel<<<dim3(4, 128), 512, 0, stream>>>(Pp, WoT, out, 512, 512);
}